// Round 10
// baseline (80.489 us; speedup 1.0000x reference)
//
#include <hip/hip_runtime.h>

#define NORB 13
#define FEAT 107
#define TWO_PI 6.28318530717958647692f
#define NN 3328                 // 256 atoms * 13 orbitals
#define ROWF (NN * 2)           // floats per row
#define R4 (NN / 2)             // 1664 float4 per row
#define EMAX 4096
#define CAP 128                 // per-atom directed-entry capacity (LDS)
#define MAXS 48                 // painted column-block slots (LDS)

// (p,q) in 13x13 block -> feature index (or -1) + scale.
// Basis l=[0,0,1,1,2], dims [1,1,3,3,5], offsets [0,1,2,5,8].
__device__ __forceinline__ void map_pq(int p, int q, int& idx, float& scl) {
    const int DIMS[5] = {1, 1, 3, 3, 5};
    const int OFFS[5] = {0, 1, 2, 5, 8};
    idx = -1; scl = 0.0f;
    int o = 0;
    #pragma unroll
    for (int i = 0; i < 5; ++i) {
        #pragma unroll
        for (int j = i; j < 5; ++j) {
            int di = DIMS[i], dj = DIMS[j];
            if (p >= OFFS[i] && p < OFFS[i] + di && q >= OFFS[j] && q < OFFS[j] + dj) {
                idx = o + (p - OFFS[i]) * dj + (q - OFFS[j]);
                scl = (i == j) ? 0.5f : 1.0f;
            }
            o += di * dj;
        }
    }
}

// ---- dispatch 1: plain grid-stride zero (proven-fast fill pattern) ----
__global__ void zero_kernel(float4* __restrict__ out, long n4) {
    long i = (long)blockIdx.x * blockDim.x + threadIdx.x;
    long stride = (long)gridDim.x * blockDim.x;
    float4 zz = make_float4(0.f, 0.f, 0.f, 0.f);
    for (; i < n4; i += stride) out[i] = zz;
}

// ---- dispatch 2: paint only the nonzero complexes (plain stores) ----
// One block per (k, atom, half-slab). Scans edge_index, aggregates all
// contributions per (a,b) block pair in LDS, then stores painted complexes.
// Runs after zero_kernel; each painted complex written by exactly one thread.
__global__ __launch_bounds__(256)
void paint_kernel(const float* __restrict__ hop, const float* __restrict__ ons,
                  const float* __restrict__ kpt, const float* __restrict__ shf,
                  const int* __restrict__ eidx, float* __restrict__ out, int E) {
    int z = blockIdx.x;                 // 0..2047
    int k = z >> 9;
    int a = (z >> 1) & 255;
    int half = z & 1;
    int rbase = half ? 7 : 0;
    int nrows = half ? 6 : 7;
    int t = threadIdx.x;

    __shared__ int ilist[CAP];          // packed (b<<13 | e<<1 | dir)
    __shared__ int nmatch;
    __shared__ float2 phl[CAP];         // per-item phase for this block's k
    __shared__ unsigned char present[256];
    __shared__ unsigned char smap[256];
    __shared__ unsigned char sblk[MAXS];
    __shared__ unsigned long long wmask[4];
    __shared__ float2 pblk[MAXS][91];   // [slot][local_row*13+q]

    if (t == 0) nmatch = 0;
    present[t] = 0;
    __syncthreads();

    // scan edge list for directed entries with source atom a
    for (int e = t; e < E; e += 256) {
        int ei = eidx[e], ej = eidx[E + e];
        if (ei == a) { int s = atomicAdd(&nmatch, 1); if (s < CAP) ilist[s] = (ej << 13) | (e << 1); }
        if (ej == a) { int s = atomicAdd(&nmatch, 1); if (s < CAP) ilist[s] = (ei << 13) | (e << 1) | 1; }
    }
    __syncthreads();
    int n = nmatch;
    int nb = n < CAP ? n : CAP;

    for (int i = t; i < nb; i += 256) present[ilist[i] >> 13] = 1;
    if (t == 0) present[a] = 1;         // diagonal always painted
    __syncthreads();

    // per-item phase (this k only)
    float kx = kpt[k * 3], ky = kpt[k * 3 + 1], kz = kpt[k * 3 + 2];
    for (int i = t; i < nb; i += 256) {
        int e = (ilist[i] >> 1) & 4095;
        float th = -TWO_PI * (kx * shf[e * 3] + ky * shf[e * 3 + 1] + kz * shf[e * 3 + 2]);
        float s, c;
        __sincosf(th, &s, &c);
        phl[i] = make_float2(c, s);
    }

    // slot assignment via ballot + prefix popcount
    unsigned long long m = __ballot(present[t] != 0);
    int w = t >> 6;
    if ((t & 63) == 0) wmask[w] = m;
    __syncthreads();
    int nslots = __popcll(wmask[0]) + __popcll(wmask[1]) +
                 __popcll(wmask[2]) + __popcll(wmask[3]);

    int nloc = nrows * 13;              // 91 or 78

    if (n <= CAP && nslots <= MAXS) {
        if (present[t]) {
            int pre = 0;
            #pragma unroll
            for (int i = 0; i < 4; ++i) if (i < w) pre += __popcll(wmask[i]);
            pre += __popcll(wmask[w] & ((1ull << (t & 63)) - 1ull));
            smap[t] = (unsigned char)pre;
            if (pre < MAXS) sblk[pre] = (unsigned char)t;
        } else {
            smap[t] = 255;
        }
        __syncthreads();

        float2* pf = &pblk[0][0];
        for (int i = t; i < nslots * 91; i += 256) pf[i] = make_float2(0.f, 0.f);
        __syncthreads();

        // paint-compute into LDS
        if (t < nloc) {
            int p = rbase + t / 13, q = t % 13;   // t == local_row*13+q
            int i0, i1; float s0, s1;
            map_pq(p, q, i0, s0);
            map_pq(q, p, i1, s1);
            {   // onsite (real) into diagonal slot
                const float* f = ons + (long)a * FEAT;
                float v = 0.f;
                if (i0 >= 0) v += s0 * f[i0];
                if (i1 >= 0) v += s1 * f[i1];
                pblk[smap[a]][t].x += v;
            }
            for (int i = 0; i < nb; ++i) {
                int pk = ilist[i];
                int b = pk >> 13;
                int e = (pk >> 1) & 4095;
                int dir = pk & 1;
                float hv = dir ? ((i1 >= 0) ? s1 * hop[(long)e * FEAT + i1] : 0.f)
                               : ((i0 >= 0) ? s0 * hop[(long)e * FEAT + i0] : 0.f);
                float2 ph = phl[i];
                float2 v = pblk[smap[b]][t];
                v.x += ph.x * hv;
                v.y += (dir ? -ph.y : ph.y) * hv;
                pblk[smap[b]][t] = v;
            }
        }
        __syncthreads();

        // store painted complexes only (plain float2 stores, 104B runs)
        float2* out2 = (float2*)out;
        int total = nslots * nloc;
        for (int u = t; u < total; u += 256) {
            int s = u / nloc;
            int v = u - s * nloc;           // local_row*13 + q
            int rr = v / 13;
            int q = v - rr * 13;
            int b = sblk[s];
            long off = (long)(k * NN + a * 13 + rbase + rr) * NN + b * 13 + q;
            out2[off] = pblk[s][v];
        }
    } else {
        // rare fallback: atomics onto already-zeroed output
        if (t < nloc) {
            int p = rbase + t / 13, q = t % 13;
            int i0, i1; float s0, s1;
            map_pq(p, q, i0, s0);
            map_pq(q, p, i1, s1);
            {
                const float* f = ons + (long)a * FEAT;
                float v = 0.f;
                if (i0 >= 0) v += s0 * f[i0];
                if (i1 >= 0) v += s1 * f[i1];
                long off = (long)(k * NN + a * 13 + p) * ROWF + (a * 13 + q) * 2;
                atomicAdd(&out[off], v);
            }
            if (n <= CAP) {
                for (int i = 0; i < nb; ++i) {
                    int pk = ilist[i];
                    int b = pk >> 13, e = (pk >> 1) & 4095, dir = pk & 1;
                    float hv = dir ? ((i1 >= 0) ? s1 * hop[(long)e * FEAT + i1] : 0.f)
                                   : ((i0 >= 0) ? s0 * hop[(long)e * FEAT + i0] : 0.f);
                    float2 ph = phl[i];
                    long off = (long)(k * NN + a * 13 + p) * ROWF + (b * 13 + q) * 2;
                    atomicAdd(&out[off], ph.x * hv);
                    atomicAdd(&out[off + 1], (dir ? -ph.y : ph.y) * hv);
                }
            } else {
                for (int e = 0; e < E; ++e) {
                    int ei = eidx[e], ej = eidx[E + e];
                    #pragma unroll
                    for (int dir = 0; dir < 2; ++dir) {
                        int sa = dir ? ej : ei, b = dir ? ei : ej;
                        if (sa != a) continue;
                        float hv = dir ? ((i1 >= 0) ? s1 * hop[(long)e * FEAT + i1] : 0.f)
                                       : ((i0 >= 0) ? s0 * hop[(long)e * FEAT + i0] : 0.f);
                        float th = -TWO_PI * (kx * shf[e*3] + ky * shf[e*3+1] + kz * shf[e*3+2]);
                        float s, c;
                        __sincosf(th, &s, &c);
                        long off = (long)(k * NN + a * 13 + p) * ROWF + (b * 13 + q) * 2;
                        atomicAdd(&out[off], c * hv);
                        atomicAdd(&out[off + 1], (dir ? -s : s) * hv);
                    }
                }
            }
        }
    }
}

// ============================ FALLBACK PATH (round-2, proven) ================

template <int CPX>
__global__ void onsite_kernel(const float* __restrict__ onsite, float* __restrict__ out,
                              int K, long nn) {
    int a = blockIdx.x;
    int t = threadIdx.x;
    if (t >= NORB * NORB) return;
    int p = t / NORB, q = t % NORB;
    int i1, i2; float s1, s2;
    map_pq(p, q, i1, s1);
    map_pq(q, p, i2, s2);
    const float* f = onsite + (long)a * FEAT;
    float v = 0.0f;
    if (i1 >= 0) v += s1 * f[i1];
    if (i2 >= 0) v += s2 * f[i2];
    long row = (long)a * NORB + p;
    long col = (long)a * NORB + q;
    for (int k = 0; k < K; ++k) {
        long off = (((long)k * nn + row) * nn + col) * CPX;
        out[off] = v;
    }
}

template <int CPX>
__global__ void edge_kernel(const float* __restrict__ hop, const float* __restrict__ kpts,
                            const float* __restrict__ shift, const int* __restrict__ eidx,
                            float* __restrict__ out, int E, int K, long nn) {
    int e = blockIdx.x;
    int t = threadIdx.x;
    __shared__ float phc[16], phs[16];
    int ei = eidx[e];
    int ej = eidx[E + e];
    if (t < K && t < 16) {
        float rx = shift[(long)e * 3 + 0];
        float ry = shift[(long)e * 3 + 1];
        float rz = shift[(long)e * 3 + 2];
        float th = -TWO_PI * (kpts[t * 3 + 0] * rx + kpts[t * 3 + 1] * ry + kpts[t * 3 + 2] * rz);
        float s, c;
        __sincosf(th, &s, &c);
        phc[t] = c; phs[t] = s;
    }
    __syncthreads();
    if (t >= NORB * NORB) return;
    int p = t / NORB, q = t % NORB;
    int idx; float scl;
    map_pq(p, q, idx, scl);
    if (idx < 0) return;
    float v = scl * hop[(long)e * FEAT + idx];
    long r1 = (long)ei * NORB + p, c1 = (long)ej * NORB + q;
    long r2 = (long)ej * NORB + q, c2 = (long)ei * NORB + p;
    for (int k = 0; k < K; ++k) {
        float pr = phc[k], pi = phs[k];
        long o1 = (((long)k * nn + r1) * nn + c1) * CPX;
        long o2 = (((long)k * nn + r2) * nn + c2) * CPX;
        atomicAdd(&out[o1], pr * v);
        atomicAdd(&out[o2], pr * v);
        if (CPX == 2) {
            atomicAdd(&out[o1 + 1], pi * v);
            atomicAdd(&out[o2 + 1], -pi * v);
        }
    }
}

// ============================================================================

extern "C" void kernel_launch(void* const* d_in, const int* in_sizes, int n_in,
                              void* d_out, int out_size, void* d_ws, size_t ws_size,
                              hipStream_t stream) {
    const float* hop  = (const float*)d_in[0];
    const float* ons  = (const float*)d_in[1];
    const float* kpt  = (const float*)d_in[2];
    const float* shf  = (const float*)d_in[3];
    const int*   eidx = (const int*)d_in[4];

    int E = in_sizes[0] / FEAT;    // 4096
    int N = in_sizes[1] / FEAT;    // 256
    int K = in_sizes[2] / 3;       // 4
    long nn = (long)N * NORB;      // 3328

    float* out = (float*)d_out;
    long knn2 = (long)K * nn * nn * 2;

    bool fast = (N == 256) && (K == 4) && (E <= EMAX) &&
                ((long)out_size == knn2);

    long n4 = (long)out_size / 4;
    zero_kernel<<<2048, 256, 0, stream>>>((float4*)out, n4);

    if (fast) {
        paint_kernel<<<2048, 256, 0, stream>>>(hop, ons, kpt, shf, eidx, out, E);
    } else {
        int cpx = ((long)out_size >= knn2) ? 2 : 1;
        if (cpx == 2) {
            onsite_kernel<2><<<N, 192, 0, stream>>>(ons, out, K, nn);
            edge_kernel<2><<<E, 192, 0, stream>>>(hop, kpt, shf, eidx, out, E, K, nn);
        } else {
            onsite_kernel<1><<<N, 192, 0, stream>>>(ons, out, K, nn);
            edge_kernel<1><<<E, 192, 0, stream>>>(hop, kpt, shf, eidx, out, E, K, nn);
        }
    }
}

// Round 11
// 75.341 us; speedup vs baseline: 1.0683x; 1.0683x over previous
//
#include <hip/hip_runtime.h>

#define NORB 13
#define FEAT 107
#define TWO_PI 6.28318530717958647692f
#define NN 3328                 // 256 atoms * 13 orbitals
#define ROWF (NN * 2)           // floats per row
#define EMAX 4096
#define CAP 128                 // per-atom directed-entry capacity (LDS)
#define MAXS 48                 // painted column-block slots (LDS)

// (p,q) in 13x13 block -> feature index (or -1) + scale.
// Basis l=[0,0,1,1,2], dims [1,1,3,3,5], offsets [0,1,2,5,8].
__device__ __forceinline__ void map_pq(int p, int q, int& idx, float& scl) {
    const int DIMS[5] = {1, 1, 3, 3, 5};
    const int OFFS[5] = {0, 1, 2, 5, 8};
    idx = -1; scl = 0.0f;
    int o = 0;
    #pragma unroll
    for (int i = 0; i < 5; ++i) {
        #pragma unroll
        for (int j = i; j < 5; ++j) {
            int di = DIMS[i], dj = DIMS[j];
            if (p >= OFFS[i] && p < OFFS[i] + di && q >= OFFS[j] && q < OFFS[j] + dj) {
                idx = o + (p - OFFS[i]) * dj + (q - OFFS[j]);
                scl = (i == j) ? 0.5f : 1.0f;
            }
            o += di * dj;
        }
    }
}

// ---- paint: only the nonzero complexes (plain stores), after memset ----
// One block per (k, atom, half-slab). Scans edge_index, aggregates all
// contributions per (a,b) block pair in LDS, then stores painted complexes.
__global__ __launch_bounds__(256)
void paint_kernel(const float* __restrict__ hop, const float* __restrict__ ons,
                  const float* __restrict__ kpt, const float* __restrict__ shf,
                  const int* __restrict__ eidx, float* __restrict__ out, int E) {
    int z = blockIdx.x;                 // 0..2047
    int k = z >> 9;
    int a = (z >> 1) & 255;
    int half = z & 1;
    int rbase = half ? 7 : 0;
    int nrows = half ? 6 : 7;
    int t = threadIdx.x;

    __shared__ int ilist[CAP];          // packed (b<<13 | e<<1 | dir)
    __shared__ int nmatch;
    __shared__ float2 phl[CAP];         // per-item phase for this block's k
    __shared__ unsigned char present[256];
    __shared__ unsigned char smap[256];
    __shared__ unsigned char sblk[MAXS];
    __shared__ unsigned long long wmask[4];
    __shared__ float2 pblk[MAXS][91];   // [slot][local_row*13+q]

    if (t == 0) nmatch = 0;
    present[t] = 0;
    __syncthreads();

    // scan edge list for directed entries with source atom a
    for (int e = t; e < E; e += 256) {
        int ei = eidx[e], ej = eidx[E + e];
        if (ei == a) { int s = atomicAdd(&nmatch, 1); if (s < CAP) ilist[s] = (ej << 13) | (e << 1); }
        if (ej == a) { int s = atomicAdd(&nmatch, 1); if (s < CAP) ilist[s] = (ei << 13) | (e << 1) | 1; }
    }
    __syncthreads();
    int n = nmatch;
    int nb = n < CAP ? n : CAP;

    for (int i = t; i < nb; i += 256) present[ilist[i] >> 13] = 1;
    if (t == 0) present[a] = 1;         // diagonal always painted
    __syncthreads();

    // per-item phase (this k only)
    float kx = kpt[k * 3], ky = kpt[k * 3 + 1], kz = kpt[k * 3 + 2];
    for (int i = t; i < nb; i += 256) {
        int e = (ilist[i] >> 1) & 4095;
        float th = -TWO_PI * (kx * shf[e * 3] + ky * shf[e * 3 + 1] + kz * shf[e * 3 + 2]);
        float s, c;
        __sincosf(th, &s, &c);
        phl[i] = make_float2(c, s);
    }

    // slot assignment via ballot + prefix popcount
    unsigned long long m = __ballot(present[t] != 0);
    int w = t >> 6;
    if ((t & 63) == 0) wmask[w] = m;
    __syncthreads();
    int nslots = __popcll(wmask[0]) + __popcll(wmask[1]) +
                 __popcll(wmask[2]) + __popcll(wmask[3]);

    int nloc = nrows * 13;              // 91 or 78

    if (n <= CAP && nslots <= MAXS) {
        if (present[t]) {
            int pre = 0;
            #pragma unroll
            for (int i = 0; i < 4; ++i) if (i < w) pre += __popcll(wmask[i]);
            pre += __popcll(wmask[w] & ((1ull << (t & 63)) - 1ull));
            smap[t] = (unsigned char)pre;
            if (pre < MAXS) sblk[pre] = (unsigned char)t;
        } else {
            smap[t] = 255;
        }
        __syncthreads();

        float2* pf = &pblk[0][0];
        for (int i = t; i < nslots * 91; i += 256) pf[i] = make_float2(0.f, 0.f);
        __syncthreads();

        // paint-compute into LDS
        if (t < nloc) {
            int p = rbase + t / 13, q = t % 13;   // t == local_row*13+q
            int i0, i1; float s0, s1;
            map_pq(p, q, i0, s0);
            map_pq(q, p, i1, s1);
            {   // onsite (real) into diagonal slot
                const float* f = ons + (long)a * FEAT;
                float v = 0.f;
                if (i0 >= 0) v += s0 * f[i0];
                if (i1 >= 0) v += s1 * f[i1];
                pblk[smap[a]][t].x += v;
            }
            for (int i = 0; i < nb; ++i) {
                int pk = ilist[i];
                int b = pk >> 13;
                int e = (pk >> 1) & 4095;
                int dir = pk & 1;
                float hv = dir ? ((i1 >= 0) ? s1 * hop[(long)e * FEAT + i1] : 0.f)
                               : ((i0 >= 0) ? s0 * hop[(long)e * FEAT + i0] : 0.f);
                float2 ph = phl[i];
                float2 v = pblk[smap[b]][t];
                v.x += ph.x * hv;
                v.y += (dir ? -ph.y : ph.y) * hv;
                pblk[smap[b]][t] = v;
            }
        }
        __syncthreads();

        // store painted complexes only (plain float2 stores)
        float2* out2 = (float2*)out;
        int total = nslots * nloc;
        for (int u = t; u < total; u += 256) {
            int s = u / nloc;
            int v = u - s * nloc;           // local_row*13 + q
            int rr = v / 13;
            int q = v - rr * 13;
            int b = sblk[s];
            long off = (long)(k * NN + a * 13 + rbase + rr) * NN + b * 13 + q;
            out2[off] = pblk[s][v];
        }
    } else {
        // rare fallback: atomics onto already-zeroed output
        if (t < nloc) {
            int p = rbase + t / 13, q = t % 13;
            int i0, i1; float s0, s1;
            map_pq(p, q, i0, s0);
            map_pq(q, p, i1, s1);
            {
                const float* f = ons + (long)a * FEAT;
                float v = 0.f;
                if (i0 >= 0) v += s0 * f[i0];
                if (i1 >= 0) v += s1 * f[i1];
                long off = (long)(k * NN + a * 13 + p) * ROWF + (a * 13 + q) * 2;
                atomicAdd(&out[off], v);
            }
            if (n <= CAP) {
                for (int i = 0; i < nb; ++i) {
                    int pk = ilist[i];
                    int b = pk >> 13, e = (pk >> 1) & 4095, dir = pk & 1;
                    float hv = dir ? ((i1 >= 0) ? s1 * hop[(long)e * FEAT + i1] : 0.f)
                                   : ((i0 >= 0) ? s0 * hop[(long)e * FEAT + i0] : 0.f);
                    float2 ph = phl[i];
                    long off = (long)(k * NN + a * 13 + p) * ROWF + (b * 13 + q) * 2;
                    atomicAdd(&out[off], ph.x * hv);
                    atomicAdd(&out[off + 1], (dir ? -ph.y : ph.y) * hv);
                }
            } else {
                for (int e = 0; e < E; ++e) {
                    int ei = eidx[e], ej = eidx[E + e];
                    #pragma unroll
                    for (int dir = 0; dir < 2; ++dir) {
                        int sa = dir ? ej : ei, b = dir ? ei : ej;
                        if (sa != a) continue;
                        float hv = dir ? ((i1 >= 0) ? s1 * hop[(long)e * FEAT + i1] : 0.f)
                                       : ((i0 >= 0) ? s0 * hop[(long)e * FEAT + i0] : 0.f);
                        float th = -TWO_PI * (kx * shf[e*3] + ky * shf[e*3+1] + kz * shf[e*3+2]);
                        float s, c;
                        __sincosf(th, &s, &c);
                        long off = (long)(k * NN + a * 13 + p) * ROWF + (b * 13 + q) * 2;
                        atomicAdd(&out[off], c * hv);
                        atomicAdd(&out[off + 1], (dir ? -s : s) * hv);
                    }
                }
            }
        }
    }
}

// ============================ FALLBACK PATH (round-2, proven) ================

template <int CPX>
__global__ void onsite_kernel(const float* __restrict__ onsite, float* __restrict__ out,
                              int K, long nn) {
    int a = blockIdx.x;
    int t = threadIdx.x;
    if (t >= NORB * NORB) return;
    int p = t / NORB, q = t % NORB;
    int i1, i2; float s1, s2;
    map_pq(p, q, i1, s1);
    map_pq(q, p, i2, s2);
    const float* f = onsite + (long)a * FEAT;
    float v = 0.0f;
    if (i1 >= 0) v += s1 * f[i1];
    if (i2 >= 0) v += s2 * f[i2];
    long row = (long)a * NORB + p;
    long col = (long)a * NORB + q;
    for (int k = 0; k < K; ++k) {
        long off = (((long)k * nn + row) * nn + col) * CPX;
        out[off] = v;
    }
}

template <int CPX>
__global__ void edge_kernel(const float* __restrict__ hop, const float* __restrict__ kpts,
                            const float* __restrict__ shift, const int* __restrict__ eidx,
                            float* __restrict__ out, int E, int K, long nn) {
    int e = blockIdx.x;
    int t = threadIdx.x;
    __shared__ float phc[16], phs[16];
    int ei = eidx[e];
    int ej = eidx[E + e];
    if (t < K && t < 16) {
        float rx = shift[(long)e * 3 + 0];
        float ry = shift[(long)e * 3 + 1];
        float rz = shift[(long)e * 3 + 2];
        float th = -TWO_PI * (kpts[t * 3 + 0] * rx + kpts[t * 3 + 1] * ry + kpts[t * 3 + 2] * rz);
        float s, c;
        __sincosf(th, &s, &c);
        phc[t] = c; phs[t] = s;
    }
    __syncthreads();
    if (t >= NORB * NORB) return;
    int p = t / NORB, q = t % NORB;
    int idx; float scl;
    map_pq(p, q, idx, scl);
    if (idx < 0) return;
    float v = scl * hop[(long)e * FEAT + idx];
    long r1 = (long)ei * NORB + p, c1 = (long)ej * NORB + q;
    long r2 = (long)ej * NORB + q, c2 = (long)ei * NORB + p;
    for (int k = 0; k < K; ++k) {
        float pr = phc[k], pi = phs[k];
        long o1 = (((long)k * nn + r1) * nn + c1) * CPX;
        long o2 = (((long)k * nn + r2) * nn + c2) * CPX;
        atomicAdd(&out[o1], pr * v);
        atomicAdd(&out[o2], pr * v);
        if (CPX == 2) {
            atomicAdd(&out[o1 + 1], pi * v);
            atomicAdd(&out[o2 + 1], -pi * v);
        }
    }
}

// ============================================================================

extern "C" void kernel_launch(void* const* d_in, const int* in_sizes, int n_in,
                              void* d_out, int out_size, void* d_ws, size_t ws_size,
                              hipStream_t stream) {
    const float* hop  = (const float*)d_in[0];
    const float* ons  = (const float*)d_in[1];
    const float* kpt  = (const float*)d_in[2];
    const float* shf  = (const float*)d_in[3];
    const int*   eidx = (const int*)d_in[4];

    int E = in_sizes[0] / FEAT;    // 4096
    int N = in_sizes[1] / FEAT;    // 256
    int K = in_sizes[2] / 3;       // 4
    long nn = (long)N * NORB;      // 3328

    float* out = (float*)d_out;
    long knn2 = (long)K * nn * nn * 2;

    bool fast = (N == 256) && (K == 4) && (E <= EMAX) &&
                ((long)out_size == knn2);

    // Zero via the runtime's tuned fill kernel (graph-capturable, async).
    hipMemsetAsync(d_out, 0, (size_t)out_size * sizeof(float), stream);

    if (fast) {
        paint_kernel<<<2048, 256, 0, stream>>>(hop, ons, kpt, shf, eidx, out, E);
    } else {
        int cpx = ((long)out_size >= knn2) ? 2 : 1;
        if (cpx == 2) {
            onsite_kernel<2><<<N, 192, 0, stream>>>(ons, out, K, nn);
            edge_kernel<2><<<E, 192, 0, stream>>>(hop, kpt, shf, eidx, out, E, K, nn);
        } else {
            onsite_kernel<1><<<N, 192, 0, stream>>>(ons, out, K, nn);
            edge_kernel<1><<<E, 192, 0, stream>>>(hop, kpt, shf, eidx, out, E, K, nn);
        }
    }
}

// Round 12
// 74.523 us; speedup vs baseline: 1.0801x; 1.0110x over previous
//
#include <hip/hip_runtime.h>

#define NORB 13
#define FEAT 107
#define TWO_PI 6.28318530717958647692f
#define NN 3328                 // 256 atoms * 13 orbitals
#define ROWF (NN * 2)           // floats per row
#define EMAX 4096
#define CAP 128                 // per-atom directed-entry capacity
#define MAXS 48                 // painted column-block slots (LDS)

// Static device scratch (module-load allocated; no hipMalloc, graph-safe).
__device__ int    g_cnt[256];                  // directed entries per atom
__device__ int    g_items[256 * CAP];          // packed (b<<13 | tid), tid=e*2+dir
__device__ float2 g_iphase[2 * EMAX * 4];      // per-item, per-k phase, sign folded

// (p,q) in 13x13 block -> feature index (or -1) + scale.
// Basis l=[0,0,1,1,2], dims [1,1,3,3,5], offsets [0,1,2,5,8].
__device__ __forceinline__ void map_pq(int p, int q, int& idx, float& scl) {
    const int DIMS[5] = {1, 1, 3, 3, 5};
    const int OFFS[5] = {0, 1, 2, 5, 8};
    idx = -1; scl = 0.0f;
    int o = 0;
    #pragma unroll
    for (int i = 0; i < 5; ++i) {
        #pragma unroll
        for (int j = i; j < 5; ++j) {
            int di = DIMS[i], dj = DIMS[j];
            if (p >= OFFS[i] && p < OFFS[i] + di && q >= OFFS[j] && q < OFFS[j] + dj) {
                idx = o + (p - OFFS[i]) * dj + (q - OFFS[j]);
                scl = (i == j) ? 0.5f : 1.0f;
            }
            o += di * dj;
        }
    }
}

__global__ void init_kernel() {
    g_cnt[threadIdx.x] = 0;       // 1 block x 256
}

// Per directed edge entry: bucket it by source atom and precompute its phase
// for all K k-points with the conjugation sign folded into the imag part.
__global__ void fill_kernel(const int* __restrict__ eidx, const float* __restrict__ kpt,
                            const float* __restrict__ shf, int E, int K) {
    int tid = blockIdx.x * blockDim.x + threadIdx.x;
    if (tid >= 2 * E) return;
    int e = tid >> 1, dir = tid & 1;
    int ei = eidx[e], ej = eidx[E + e];
    int a = dir ? ej : ei;
    int b = dir ? ei : ej;
    int slot = atomicAdd(&g_cnt[a], 1);
    if (slot < CAP) g_items[a * CAP + slot] = (b << 13) | tid;
    float rx = shf[e * 3 + 0], ry = shf[e * 3 + 1], rz = shf[e * 3 + 2];
    for (int k = 0; k < K && k < 4; ++k) {
        float th = -TWO_PI * (kpt[k * 3] * rx + kpt[k * 3 + 1] * ry + kpt[k * 3 + 2] * rz);
        float s, c;
        __sincosf(th, &s, &c);
        g_iphase[tid * 4 + k] = make_float2(c, dir ? -s : s);
    }
}

// One block per (k, atom, half-slab). Loads its atom's prebuilt bucket,
// aggregates per (a,b) block pair in LDS, stores painted complexes only.
// Runs after memset; each painted complex written by exactly one thread.
__global__ __launch_bounds__(256)
void paint_kernel(const float* __restrict__ hop, const float* __restrict__ ons,
                  const float* __restrict__ kpt, const float* __restrict__ shf,
                  const int* __restrict__ eidx, float* __restrict__ out, int E) {
    int z = blockIdx.x;                 // 0..2047
    int k = z >> 9;
    int a = (z >> 1) & 255;
    int half = z & 1;
    int rbase = half ? 7 : 0;
    int nrows = half ? 6 : 7;
    int t = threadIdx.x;

    __shared__ int ilist[CAP];          // packed (b<<13 | tid)
    __shared__ float2 phl[CAP];         // per-item phase for this block's k
    __shared__ unsigned char present[256];
    __shared__ unsigned char smap[256];
    __shared__ unsigned char sblk[MAXS];
    __shared__ unsigned long long wmask[4];
    __shared__ float2 pblk[MAXS][91];   // [slot][local_row*13+q]

    int n = g_cnt[a];
    int nb = n < CAP ? n : CAP;
    present[t] = 0;
    __syncthreads();

    if (t < nb) {
        int pk = g_items[a * CAP + t];
        ilist[t] = pk;
        phl[t] = g_iphase[(pk & 8191) * 4 + k];
        present[pk >> 13] = 1;
    }
    if (t == 0) present[a] = 1;         // diagonal always painted
    __syncthreads();

    // slot assignment via ballot + prefix popcount
    unsigned long long m = __ballot(present[t] != 0);
    int w = t >> 6;
    if ((t & 63) == 0) wmask[w] = m;
    __syncthreads();
    int nslots = __popcll(wmask[0]) + __popcll(wmask[1]) +
                 __popcll(wmask[2]) + __popcll(wmask[3]);

    int nloc = nrows * 13;              // 91 or 78

    if (n <= CAP && nslots <= MAXS) {
        if (present[t]) {
            int pre = 0;
            #pragma unroll
            for (int i = 0; i < 4; ++i) if (i < w) pre += __popcll(wmask[i]);
            pre += __popcll(wmask[w] & ((1ull << (t & 63)) - 1ull));
            smap[t] = (unsigned char)pre;
            if (pre < MAXS) sblk[pre] = (unsigned char)t;
        } else {
            smap[t] = 255;
        }
        __syncthreads();

        float2* pf = &pblk[0][0];
        for (int i = t; i < nslots * 91; i += 256) pf[i] = make_float2(0.f, 0.f);
        __syncthreads();

        // paint-compute into LDS
        if (t < nloc) {
            int p = rbase + t / 13, q = t % 13;   // t == local_row*13+q
            int i0, i1; float s0, s1;
            map_pq(p, q, i0, s0);
            map_pq(q, p, i1, s1);
            {   // onsite (real) into diagonal slot
                const float* f = ons + (long)a * FEAT;
                float v = 0.f;
                if (i0 >= 0) v += s0 * f[i0];
                if (i1 >= 0) v += s1 * f[i1];
                pblk[smap[a]][t].x += v;
            }
            for (int i = 0; i < nb; ++i) {
                int pk = ilist[i];
                int b = pk >> 13;
                int e = (pk >> 1) & 4095;
                int dir = pk & 1;
                float hv = dir ? ((i1 >= 0) ? s1 * hop[(long)e * FEAT + i1] : 0.f)
                               : ((i0 >= 0) ? s0 * hop[(long)e * FEAT + i0] : 0.f);
                float2 ph = phl[i];
                float2 v = pblk[smap[b]][t];
                v.x += ph.x * hv;
                v.y += ph.y * hv;          // sign already folded in fill
                pblk[smap[b]][t] = v;
            }
        }
        __syncthreads();

        // store painted complexes only (plain float2 stores)
        float2* out2 = (float2*)out;
        int total = nslots * nloc;
        for (int u = t; u < total; u += 256) {
            int s = u / nloc;
            int v = u - s * nloc;           // local_row*13 + q
            int rr = v / 13;
            int q = v - rr * 13;
            int b = sblk[s];
            long off = (long)(k * NN + a * 13 + rbase + rr) * NN + b * 13 + q;
            out2[off] = pblk[s][v];
        }
    } else {
        // rare fallback: atomics onto already-zeroed output
        float kx = kpt[k * 3], ky = kpt[k * 3 + 1], kz = kpt[k * 3 + 2];
        if (t < nloc) {
            int p = rbase + t / 13, q = t % 13;
            int i0, i1; float s0, s1;
            map_pq(p, q, i0, s0);
            map_pq(q, p, i1, s1);
            {
                const float* f = ons + (long)a * FEAT;
                float v = 0.f;
                if (i0 >= 0) v += s0 * f[i0];
                if (i1 >= 0) v += s1 * f[i1];
                long off = (long)(k * NN + a * 13 + p) * ROWF + (a * 13 + q) * 2;
                atomicAdd(&out[off], v);
            }
            if (n <= CAP) {
                for (int i = 0; i < nb; ++i) {
                    int pk = ilist[i];
                    int b = pk >> 13, e = (pk >> 1) & 4095;
                    int dir = pk & 1;
                    float hv = dir ? ((i1 >= 0) ? s1 * hop[(long)e * FEAT + i1] : 0.f)
                                   : ((i0 >= 0) ? s0 * hop[(long)e * FEAT + i0] : 0.f);
                    float2 ph = phl[i];
                    long off = (long)(k * NN + a * 13 + p) * ROWF + (b * 13 + q) * 2;
                    atomicAdd(&out[off], ph.x * hv);
                    atomicAdd(&out[off + 1], ph.y * hv);
                }
            } else {
                for (int e = 0; e < E; ++e) {
                    int ei = eidx[e], ej = eidx[E + e];
                    #pragma unroll
                    for (int dir = 0; dir < 2; ++dir) {
                        int sa = dir ? ej : ei, b = dir ? ei : ej;
                        if (sa != a) continue;
                        float hv = dir ? ((i1 >= 0) ? s1 * hop[(long)e * FEAT + i1] : 0.f)
                                       : ((i0 >= 0) ? s0 * hop[(long)e * FEAT + i0] : 0.f);
                        float th = -TWO_PI * (kx * shf[e*3] + ky * shf[e*3+1] + kz * shf[e*3+2]);
                        float s, c;
                        __sincosf(th, &s, &c);
                        long off = (long)(k * NN + a * 13 + p) * ROWF + (b * 13 + q) * 2;
                        atomicAdd(&out[off], c * hv);
                        atomicAdd(&out[off + 1], (dir ? -s : s) * hv);
                    }
                }
            }
        }
    }
}

// ============================ FALLBACK PATH (round-2, proven) ================

template <int CPX>
__global__ void onsite_kernel(const float* __restrict__ onsite, float* __restrict__ out,
                              int K, long nn) {
    int a = blockIdx.x;
    int t = threadIdx.x;
    if (t >= NORB * NORB) return;
    int p = t / NORB, q = t % NORB;
    int i1, i2; float s1, s2;
    map_pq(p, q, i1, s1);
    map_pq(q, p, i2, s2);
    const float* f = onsite + (long)a * FEAT;
    float v = 0.0f;
    if (i1 >= 0) v += s1 * f[i1];
    if (i2 >= 0) v += s2 * f[i2];
    long row = (long)a * NORB + p;
    long col = (long)a * NORB + q;
    for (int k = 0; k < K; ++k) {
        long off = (((long)k * nn + row) * nn + col) * CPX;
        out[off] = v;
    }
}

template <int CPX>
__global__ void edge_kernel(const float* __restrict__ hop, const float* __restrict__ kpts,
                            const float* __restrict__ shift, const int* __restrict__ eidx,
                            float* __restrict__ out, int E, int K, long nn) {
    int e = blockIdx.x;
    int t = threadIdx.x;
    __shared__ float phc[16], phs[16];
    int ei = eidx[e];
    int ej = eidx[E + e];
    if (t < K && t < 16) {
        float rx = shift[(long)e * 3 + 0];
        float ry = shift[(long)e * 3 + 1];
        float rz = shift[(long)e * 3 + 2];
        float th = -TWO_PI * (kpts[t * 3 + 0] * rx + kpts[t * 3 + 1] * ry + kpts[t * 3 + 2] * rz);
        float s, c;
        __sincosf(th, &s, &c);
        phc[t] = c; phs[t] = s;
    }
    __syncthreads();
    if (t >= NORB * NORB) return;
    int p = t / NORB, q = t % NORB;
    int idx; float scl;
    map_pq(p, q, idx, scl);
    if (idx < 0) return;
    float v = scl * hop[(long)e * FEAT + idx];
    long r1 = (long)ei * NORB + p, c1 = (long)ej * NORB + q;
    long r2 = (long)ej * NORB + q, c2 = (long)ei * NORB + p;
    for (int k = 0; k < K; ++k) {
        float pr = phc[k], pi = phs[k];
        long o1 = (((long)k * nn + r1) * nn + c1) * CPX;
        long o2 = (((long)k * nn + r2) * nn + c2) * CPX;
        atomicAdd(&out[o1], pr * v);
        atomicAdd(&out[o2], pr * v);
        if (CPX == 2) {
            atomicAdd(&out[o1 + 1], pi * v);
            atomicAdd(&out[o2 + 1], -pi * v);
        }
    }
}

// ============================================================================

extern "C" void kernel_launch(void* const* d_in, const int* in_sizes, int n_in,
                              void* d_out, int out_size, void* d_ws, size_t ws_size,
                              hipStream_t stream) {
    const float* hop  = (const float*)d_in[0];
    const float* ons  = (const float*)d_in[1];
    const float* kpt  = (const float*)d_in[2];
    const float* shf  = (const float*)d_in[3];
    const int*   eidx = (const int*)d_in[4];

    int E = in_sizes[0] / FEAT;    // 4096
    int N = in_sizes[1] / FEAT;    // 256
    int K = in_sizes[2] / 3;       // 4
    long nn = (long)N * NORB;      // 3328

    float* out = (float*)d_out;
    long knn2 = (long)K * nn * nn * 2;

    bool fast = (N == 256) && (K == 4) && (E <= EMAX) &&
                ((long)out_size == knn2);

    // Zero via the runtime's fill kernel (HBM write-compressed for zeros).
    hipMemsetAsync(d_out, 0, (size_t)out_size * sizeof(float), stream);

    if (fast) {
        init_kernel<<<1, 256, 0, stream>>>();
        fill_kernel<<<(2 * E + 255) / 256, 256, 0, stream>>>(eidx, kpt, shf, E, K);
        paint_kernel<<<2048, 256, 0, stream>>>(hop, ons, kpt, shf, eidx, out, E);
    } else {
        int cpx = ((long)out_size >= knn2) ? 2 : 1;
        if (cpx == 2) {
            onsite_kernel<2><<<N, 192, 0, stream>>>(ons, out, K, nn);
            edge_kernel<2><<<E, 192, 0, stream>>>(hop, kpt, shf, eidx, out, E, K, nn);
        } else {
            onsite_kernel<1><<<N, 192, 0, stream>>>(ons, out, K, nn);
            edge_kernel<1><<<E, 192, 0, stream>>>(hop, kpt, shf, eidx, out, E, K, nn);
        }
    }
}

// Round 13
// 74.447 us; speedup vs baseline: 1.0812x; 1.0010x over previous
//
#include <hip/hip_runtime.h>

#define NORB 13
#define FEAT 107
#define TWO_PI 6.28318530717958647692f
#define NN 3328                 // 256 atoms * 13 orbitals
#define ROWF (NN * 2)           // floats per row
#define R4 (NN / 2)             // 1664 float4 per row
#define EMAX 4096
#define CAP 128                 // per-atom directed-entry capacity
#define MAXS 48                 // painted column-block slots (LDS)

// Static device scratch (module-load allocated; no hipMalloc, graph-safe).
__device__ int    g_cnt[256];                  // directed entries per atom
__device__ int    g_items[256 * CAP];          // packed (b<<13 | tid), tid=e*2+dir
__device__ float2 g_iphase[2 * EMAX * 4];      // per-item, per-k phase, sign folded

// (p,q) in 13x13 block -> feature index (or -1) + scale.
// Basis l=[0,0,1,1,2], dims [1,1,3,3,5], offsets [0,1,2,5,8].
__device__ __forceinline__ void map_pq(int p, int q, int& idx, float& scl) {
    const int DIMS[5] = {1, 1, 3, 3, 5};
    const int OFFS[5] = {0, 1, 2, 5, 8};
    idx = -1; scl = 0.0f;
    int o = 0;
    #pragma unroll
    for (int i = 0; i < 5; ++i) {
        #pragma unroll
        for (int j = i; j < 5; ++j) {
            int di = DIMS[i], dj = DIMS[j];
            if (p >= OFFS[i] && p < OFFS[i] + di && q >= OFFS[j] && q < OFFS[j] + dj) {
                idx = o + (p - OFFS[i]) * dj + (q - OFFS[j]);
                scl = (i == j) ? 0.5f : 1.0f;
            }
            o += di * dj;
        }
    }
}

__global__ void init_kernel() {
    g_cnt[threadIdx.x] = 0;       // 1 block x 256
}

// Per directed edge entry: bucket by source atom; precompute per-k phase with
// the conjugation sign folded into the imag part.
__global__ void fill_kernel(const int* __restrict__ eidx, const float* __restrict__ kpt,
                            const float* __restrict__ shf, int E, int K) {
    int tid = blockIdx.x * blockDim.x + threadIdx.x;
    if (tid >= 2 * E) return;
    int e = tid >> 1, dir = tid & 1;
    int ei = eidx[e], ej = eidx[E + e];
    int a = dir ? ej : ei;
    int b = dir ? ei : ej;
    int slot = atomicAdd(&g_cnt[a], 1);
    if (slot < CAP) g_items[a * CAP + slot] = (b << 13) | tid;
    float rx = shf[e * 3 + 0], ry = shf[e * 3 + 1], rz = shf[e * 3 + 2];
    for (int k = 0; k < K && k < 4; ++k) {
        float th = -TWO_PI * (kpt[k * 3] * rx + kpt[k * 3 + 1] * ry + kpt[k * 3 + 2] * rz);
        float s, c;
        __sincosf(th, &s, &c);
        g_iphase[tid * 4 + k] = make_float2(c, dir ? -s : s);
    }
}

// One block per (k, atom, half-slab). Loads its atom's prebuilt bucket,
// aggregates per (a,b) block pair in LDS, then writes each painted run as
// aligned float4s composed from LDS (halo words = neighbor-slot value or
// zero -> idempotent with memset and with the neighbor's own writes).
__global__ __launch_bounds__(256)
void paint_kernel(const float* __restrict__ hop, const float* __restrict__ ons,
                  const float* __restrict__ kpt, const float* __restrict__ shf,
                  const int* __restrict__ eidx, float* __restrict__ out, int E) {
    int z = blockIdx.x;                 // 0..2047
    int k = z >> 9;
    int a = (z >> 1) & 255;
    int half = z & 1;
    int rbase = half ? 7 : 0;
    int nrows = half ? 6 : 7;
    int t = threadIdx.x;

    __shared__ int ilist[CAP];          // packed (b<<13 | tid)
    __shared__ float2 phl[CAP];         // per-item phase for this block's k
    __shared__ unsigned char present[256];
    __shared__ unsigned char smap[256];
    __shared__ unsigned char sblk[MAXS];
    __shared__ unsigned long long wmask[4];
    __shared__ float2 pblk[MAXS][91];   // [slot][local_row*13+q]

    int n = g_cnt[a];
    int nb = n < CAP ? n : CAP;
    present[t] = 0;
    __syncthreads();

    if (t < nb) {
        int pk = g_items[a * CAP + t];
        ilist[t] = pk;
        phl[t] = g_iphase[(pk & 8191) * 4 + k];
        present[pk >> 13] = 1;
    }
    if (t == 0) present[a] = 1;         // diagonal always painted
    __syncthreads();

    // slot assignment via ballot + prefix popcount
    unsigned long long m = __ballot(present[t] != 0);
    int w = t >> 6;
    if ((t & 63) == 0) wmask[w] = m;
    __syncthreads();
    int nslots = __popcll(wmask[0]) + __popcll(wmask[1]) +
                 __popcll(wmask[2]) + __popcll(wmask[3]);

    int nloc = nrows * 13;              // 91 or 78

    if (n <= CAP && nslots <= MAXS) {
        if (present[t]) {
            int pre = 0;
            #pragma unroll
            for (int i = 0; i < 4; ++i) if (i < w) pre += __popcll(wmask[i]);
            pre += __popcll(wmask[w] & ((1ull << (t & 63)) - 1ull));
            smap[t] = (unsigned char)pre;
            if (pre < MAXS) sblk[pre] = (unsigned char)t;
        } else {
            smap[t] = 255;
        }
        __syncthreads();

        float2* pf = &pblk[0][0];
        for (int i = t; i < nslots * 91; i += 256) pf[i] = make_float2(0.f, 0.f);
        __syncthreads();

        // paint-compute into LDS
        if (t < nloc) {
            int p = rbase + t / 13, q = t % 13;   // t == local_row*13+q
            int i0, i1; float s0, s1;
            map_pq(p, q, i0, s0);
            map_pq(q, p, i1, s1);
            {   // onsite (real) into diagonal slot
                const float* f = ons + (long)a * FEAT;
                float v = 0.f;
                if (i0 >= 0) v += s0 * f[i0];
                if (i1 >= 0) v += s1 * f[i1];
                pblk[smap[a]][t].x += v;
            }
            for (int i = 0; i < nb; ++i) {
                int pk = ilist[i];
                int b = pk >> 13;
                int e = (pk >> 1) & 4095;
                int dir = pk & 1;
                float hv = dir ? ((i1 >= 0) ? s1 * hop[(long)e * FEAT + i1] : 0.f)
                               : ((i0 >= 0) ? s0 * hop[(long)e * FEAT + i0] : 0.f);
                float2 ph = phl[i];
                float2 v = pblk[smap[b]][t];
                v.x += ph.x * hv;
                v.y += ph.y * hv;          // sign already folded in fill
                pblk[smap[b]][t] = v;
            }
        }
        __syncthreads();

        // ---- store: per (row, slot) run as aligned float4s (7 lanes of 8) ----
        // Task order rr-major: a wave's 8 tasks hit 8 slots in the SAME row.
        float4* out4 = (float4*)out;
        int ntask = nslots * nrows * 8;
        for (int u = t; u < ntask; u += 256) {
            int lane = u & 7;
            int rem = u >> 3;
            int s = rem % nslots;          // slot fastest after lane
            int rr = rem / nslots;
            int b = sblk[s];
            int f4s = (13 * b) >> 1;               // first float4 of run
            int f4e = (13 * b + 12) >> 1;          // last float4 of run
            int f4 = f4s + lane;
            if (f4 > f4e) continue;
            int cc0 = 2 * f4, cc1 = cc0 + 1;
            float4 v;
            {
                int bc = (unsigned)cc0 / 13u;
                int mm = smap[bc];
                if (mm != 255) { float2 pv = pblk[mm][rr * 13 + (cc0 - 13 * bc)]; v.x = pv.x; v.y = pv.y; }
                else           { v.x = 0.f; v.y = 0.f; }
            }
            {
                int bc = (unsigned)cc1 / 13u;
                int mm = smap[bc];
                if (mm != 255) { float2 pv = pblk[mm][rr * 13 + (cc1 - 13 * bc)]; v.z = pv.x; v.w = pv.y; }
                else           { v.z = 0.f; v.w = 0.f; }
            }
            long off4 = (long)(k * NN + a * 13 + rbase + rr) * R4 + f4;
            out4[off4] = v;
        }
    } else {
        // rare fallback: atomics onto already-zeroed output
        float kx = kpt[k * 3], ky = kpt[k * 3 + 1], kz = kpt[k * 3 + 2];
        if (t < nloc) {
            int p = rbase + t / 13, q = t % 13;
            int i0, i1; float s0, s1;
            map_pq(p, q, i0, s0);
            map_pq(q, p, i1, s1);
            {
                const float* f = ons + (long)a * FEAT;
                float v = 0.f;
                if (i0 >= 0) v += s0 * f[i0];
                if (i1 >= 0) v += s1 * f[i1];
                long off = (long)(k * NN + a * 13 + p) * ROWF + (a * 13 + q) * 2;
                atomicAdd(&out[off], v);
            }
            if (n <= CAP) {
                for (int i = 0; i < nb; ++i) {
                    int pk = ilist[i];
                    int b = pk >> 13, e = (pk >> 1) & 4095;
                    int dir = pk & 1;
                    float hv = dir ? ((i1 >= 0) ? s1 * hop[(long)e * FEAT + i1] : 0.f)
                                   : ((i0 >= 0) ? s0 * hop[(long)e * FEAT + i0] : 0.f);
                    float2 ph = phl[i];
                    long off = (long)(k * NN + a * 13 + p) * ROWF + (b * 13 + q) * 2;
                    atomicAdd(&out[off], ph.x * hv);
                    atomicAdd(&out[off + 1], ph.y * hv);
                }
            } else {
                for (int e = 0; e < E; ++e) {
                    int ei = eidx[e], ej = eidx[E + e];
                    #pragma unroll
                    for (int dir = 0; dir < 2; ++dir) {
                        int sa = dir ? ej : ei, b = dir ? ei : ej;
                        if (sa != a) continue;
                        float hv = dir ? ((i1 >= 0) ? s1 * hop[(long)e * FEAT + i1] : 0.f)
                                       : ((i0 >= 0) ? s0 * hop[(long)e * FEAT + i0] : 0.f);
                        float th = -TWO_PI * (kx * shf[e*3] + ky * shf[e*3+1] + kz * shf[e*3+2]);
                        float s, c;
                        __sincosf(th, &s, &c);
                        long off = (long)(k * NN + a * 13 + p) * ROWF + (b * 13 + q) * 2;
                        atomicAdd(&out[off], c * hv);
                        atomicAdd(&out[off + 1], (dir ? -s : s) * hv);
                    }
                }
            }
        }
    }
}

// ============================ FALLBACK PATH (round-2, proven) ================

template <int CPX>
__global__ void onsite_kernel(const float* __restrict__ onsite, float* __restrict__ out,
                              int K, long nn) {
    int a = blockIdx.x;
    int t = threadIdx.x;
    if (t >= NORB * NORB) return;
    int p = t / NORB, q = t % NORB;
    int i1, i2; float s1, s2;
    map_pq(p, q, i1, s1);
    map_pq(q, p, i2, s2);
    const float* f = onsite + (long)a * FEAT;
    float v = 0.0f;
    if (i1 >= 0) v += s1 * f[i1];
    if (i2 >= 0) v += s2 * f[i2];
    long row = (long)a * NORB + p;
    long col = (long)a * NORB + q;
    for (int k = 0; k < K; ++k) {
        long off = (((long)k * nn + row) * nn + col) * CPX;
        out[off] = v;
    }
}

template <int CPX>
__global__ void edge_kernel(const float* __restrict__ hop, const float* __restrict__ kpts,
                            const float* __restrict__ shift, const int* __restrict__ eidx,
                            float* __restrict__ out, int E, int K, long nn) {
    int e = blockIdx.x;
    int t = threadIdx.x;
    __shared__ float phc[16], phs[16];
    int ei = eidx[e];
    int ej = eidx[E + e];
    if (t < K && t < 16) {
        float rx = shift[(long)e * 3 + 0];
        float ry = shift[(long)e * 3 + 1];
        float rz = shift[(long)e * 3 + 2];
        float th = -TWO_PI * (kpts[t * 3 + 0] * rx + kpts[t * 3 + 1] * ry + kpts[t * 3 + 2] * rz);
        float s, c;
        __sincosf(th, &s, &c);
        phc[t] = c; phs[t] = s;
    }
    __syncthreads();
    if (t >= NORB * NORB) return;
    int p = t / NORB, q = t % NORB;
    int idx; float scl;
    map_pq(p, q, idx, scl);
    if (idx < 0) return;
    float v = scl * hop[(long)e * FEAT + idx];
    long r1 = (long)ei * NORB + p, c1 = (long)ej * NORB + q;
    long r2 = (long)ej * NORB + q, c2 = (long)ei * NORB + p;
    for (int k = 0; k < K; ++k) {
        float pr = phc[k], pi = phs[k];
        long o1 = (((long)k * nn + r1) * nn + c1) * CPX;
        long o2 = (((long)k * nn + r2) * nn + c2) * CPX;
        atomicAdd(&out[o1], pr * v);
        atomicAdd(&out[o2], pr * v);
        if (CPX == 2) {
            atomicAdd(&out[o1 + 1], pi * v);
            atomicAdd(&out[o2 + 1], -pi * v);
        }
    }
}

// ============================================================================

extern "C" void kernel_launch(void* const* d_in, const int* in_sizes, int n_in,
                              void* d_out, int out_size, void* d_ws, size_t ws_size,
                              hipStream_t stream) {
    const float* hop  = (const float*)d_in[0];
    const float* ons  = (const float*)d_in[1];
    const float* kpt  = (const float*)d_in[2];
    const float* shf  = (const float*)d_in[3];
    const int*   eidx = (const int*)d_in[4];

    int E = in_sizes[0] / FEAT;    // 4096
    int N = in_sizes[1] / FEAT;    // 256
    int K = in_sizes[2] / 3;       // 4
    long nn = (long)N * NORB;      // 3328

    float* out = (float*)d_out;
    long knn2 = (long)K * nn * nn * 2;

    bool fast = (N == 256) && (K == 4) && (E <= EMAX) &&
                ((long)out_size == knn2);

    // Zero via the runtime's fill kernel (HBM write-compressed for zeros).
    hipMemsetAsync(d_out, 0, (size_t)out_size * sizeof(float), stream);

    if (fast) {
        init_kernel<<<1, 256, 0, stream>>>();
        fill_kernel<<<(2 * E + 255) / 256, 256, 0, stream>>>(eidx, kpt, shf, E, K);
        paint_kernel<<<2048, 256, 0, stream>>>(hop, ons, kpt, shf, eidx, out, E);
    } else {
        int cpx = ((long)out_size >= knn2) ? 2 : 1;
        if (cpx == 2) {
            onsite_kernel<2><<<N, 192, 0, stream>>>(ons, out, K, nn);
            edge_kernel<2><<<E, 192, 0, stream>>>(hop, kpt, shf, eidx, out, E, K, nn);
        } else {
            onsite_kernel<1><<<N, 192, 0, stream>>>(ons, out, K, nn);
            edge_kernel<1><<<E, 192, 0, stream>>>(hop, kpt, shf, eidx, out, E, K, nn);
        }
    }
}